// Round 1
// baseline (1377.789 us; speedup 1.0000x reference)
//
#include <hip/hip_runtime.h>
#include <math.h>

// -------------------- degree / dinv --------------------

__global__ void deg_init(float* __restrict__ deg, int n) {
    int i = blockIdx.x * blockDim.x + threadIdx.x;
    if (i < n) deg[i] = 1.0f;   // self-loop contributes 1
}

__global__ void deg_count(const int* __restrict__ dst, float* __restrict__ deg, int E) {
    int i = blockIdx.x * blockDim.x + threadIdx.x;
    if (i < E) atomicAdd(&deg[dst[i]], 1.0f);
}

__global__ void deg_to_dinv(float* __restrict__ deg, int n) {
    int i = blockIdx.x * blockDim.x + threadIdx.x;
    if (i < n) deg[i] = rsqrtf(deg[i]);
}

// -------------------- GEMM: H[v][m] = dinv[v] * sum_k relu?(X[v][k]) * W[k][m] --------------------
// 16 nodes per block, 256 threads: thread (nl = tid>>6 in 0..3, col = tid&63)
// handles nodes n0 + nl + 4*u for u in 0..3.

__global__ __launch_bounds__(256) void gemm_scale(
    const float* __restrict__ X, const float* __restrict__ W,
    const float* __restrict__ dinv, float* __restrict__ H,
    int n, int K, int M, int relu_in)
{
    __shared__ float wS[128 * 64];   // max K*M = 32 KB
    __shared__ float xS[16 * 128];   // 16 node rows, max K=128

    const int tid = threadIdx.x;
    const int n0  = blockIdx.x * 16;

    for (int i = tid; i < K * M; i += 256) wS[i] = W[i];
    for (int i = tid; i < 16 * K; i += 256) {
        int r = i / K, c = i - r * K;
        int node = n0 + r;
        float v = 0.0f;
        if (node < n) v = X[(size_t)node * K + c];
        if (relu_in) v = fmaxf(v, 0.0f);
        xS[i] = v;
    }
    __syncthreads();

    const int col = tid & 63;
    const int nl  = tid >> 6;

    float acc[4] = {0.f, 0.f, 0.f, 0.f};
    if (col < M) {
        for (int k = 0; k < K; ++k) {
            float wv = wS[k * M + col];
            acc[0] += xS[(nl + 0)  * K + k] * wv;
            acc[1] += xS[(nl + 4)  * K + k] * wv;
            acc[2] += xS[(nl + 8)  * K + k] * wv;
            acc[3] += xS[(nl + 12) * K + k] * wv;
        }
        #pragma unroll
        for (int u = 0; u < 4; ++u) {
            int node = n0 + nl + 4 * u;
            if (node < n) H[(size_t)node * M + col] = acc[u] * dinv[node];
        }
    }
}

// -------------------- aggregation --------------------
// OUT[v][j] = b[j] + H[v][j]*dinv[v]   (bias + self-loop; H already carries one dinv)

__global__ void agg_init(const float* __restrict__ H, const float* __restrict__ dinv,
                         const float* __restrict__ b, float* __restrict__ OUT,
                         int n, int M)
{
    int t = blockIdx.x * blockDim.x + threadIdx.x;
    if (t < n * M) {
        int v = t / M, j = t - v * M;
        OUT[t] = b[j] + H[t] * dinv[v];
    }
}

// one wave per edge: OUT[dst][j] += H[src][j] * dinv[dst]
__global__ __launch_bounds__(256) void agg_scatter(
    const int* __restrict__ src, const int* __restrict__ dst,
    const float* __restrict__ H, const float* __restrict__ dinv,
    float* __restrict__ OUT, int E, int M)
{
    int wave = blockIdx.x * (blockDim.x >> 6) + (threadIdx.x >> 6);
    int lane = threadIdx.x & 63;
    if (wave >= E) return;
    int s = src[wave];
    int d = dst[wave];
    float nrm = dinv[d];
    if (lane < M) {
        float v = H[(size_t)s * M + lane] * nrm;
        atomicAdd(&OUT[(size_t)d * M + lane], v);
    }
}

// -------------------- relu + log_softmax (wave per node, M<=64) --------------------

__global__ __launch_bounds__(256) void logsoftmax_relu(
    const float* __restrict__ Z, float* __restrict__ out, int n, int M)
{
    int node = blockIdx.x * (blockDim.x >> 6) + (threadIdx.x >> 6);
    int lane = threadIdx.x & 63;
    if (node >= n) return;

    float z = -INFINITY;
    if (lane < M) z = fmaxf(Z[(size_t)node * M + lane], 0.0f);

    float m = z;
    #pragma unroll
    for (int o = 32; o >= 1; o >>= 1) m = fmaxf(m, __shfl_xor(m, o, 64));

    float e = (lane < M) ? expf(z - m) : 0.0f;
    float s = e;
    #pragma unroll
    for (int o = 32; o >= 1; o >>= 1) s += __shfl_xor(s, o, 64);

    if (lane < M) out[(size_t)node * M + lane] = z - m - logf(s);
}

// -------------------- launch --------------------

extern "C" void kernel_launch(void* const* d_in, const int* in_sizes, int n_in,
                              void* d_out, int out_size, void* d_ws, size_t ws_size,
                              hipStream_t stream)
{
    const float* x  = (const float*)d_in[0];
    const int*   ei = (const int*)  d_in[1];
    const float* W1 = (const float*)d_in[2];
    const float* b1 = (const float*)d_in[3];
    const float* W2 = (const float*)d_in[4];
    const float* b2 = (const float*)d_in[5];
    const float* W3 = (const float*)d_in[6];
    const float* b3 = (const float*)d_in[7];

    const int F_IN = 128, HID = 64, NCLS = 40;
    const int n = in_sizes[0] / F_IN;      // 100000
    const int E = in_sizes[1] / 2;         // 1600000
    const int* src = ei;
    const int* dst = ei + E;
    float* out = (float*)d_out;

    // workspace layout
    char* w = (char*)d_ws;
    float* dinv = (float*)w;                                   // n floats
    size_t off  = (((size_t)n * 4) + 255) & ~(size_t)255;
    float* H    = (float*)(w + off);                           // n*64 floats
    float* A    = H + (size_t)n * 64;                          // n*64 floats

    const int BLK = 256;
    auto cdiv = [](int a, int b) { return (a + b - 1) / b; };

    // degree -> dinv (stored in dinv)
    deg_init   <<<cdiv(n, BLK), BLK, 0, stream>>>(dinv, n);
    deg_count  <<<cdiv(E, BLK), BLK, 0, stream>>>(dst, dinv, E);
    deg_to_dinv<<<cdiv(n, BLK), BLK, 0, stream>>>(dinv, n);

    // ---- layer 1: x(128) -> 64 ----
    gemm_scale <<<cdiv(n, 16), BLK, 0, stream>>>(x, W1, dinv, H, n, F_IN, HID, 0);
    agg_init   <<<cdiv(n * HID, BLK), BLK, 0, stream>>>(H, dinv, b1, A, n, HID);
    agg_scatter<<<cdiv(E, 4), BLK, 0, stream>>>(src, dst, H, dinv, A, E, HID);

    // ---- layer 2: relu(A)(64) -> 64 ----
    gemm_scale <<<cdiv(n, 16), BLK, 0, stream>>>(A, W2, dinv, H, n, HID, HID, 1);
    agg_init   <<<cdiv(n * HID, BLK), BLK, 0, stream>>>(H, dinv, b2, A, n, HID);
    agg_scatter<<<cdiv(E, 4), BLK, 0, stream>>>(src, dst, H, dinv, A, E, HID);

    // ---- layer 3: relu(A)(64) -> 40 ----
    gemm_scale <<<cdiv(n, 16), BLK, 0, stream>>>(A, W3, dinv, H, n, HID, NCLS, 1);
    agg_init   <<<cdiv(n * NCLS, BLK), BLK, 0, stream>>>(H, dinv, b3, A, n, NCLS);
    agg_scatter<<<cdiv(E, 4), BLK, 0, stream>>>(src, dst, H, dinv, A, E, NCLS);

    // ---- relu + log_softmax ----
    logsoftmax_relu<<<cdiv(n, 4), BLK, 0, stream>>>(A, out, n, NCLS);
}

// Round 2
// 793.310 us; speedup vs baseline: 1.7368x; 1.7368x over previous
//
#include <hip/hip_runtime.h>
#include <math.h>

// ==================== small utility kernels ====================

__global__ void zero_int(int* __restrict__ p, int n) {
    int i = blockIdx.x * blockDim.x + threadIdx.x;
    if (i < n) p[i] = 0;
}

// deg = cnt + 1 (self loop); dinv = rsqrt(deg)
__global__ void make_dinv(const int* __restrict__ cnt, float* __restrict__ dinv, int n) {
    int i = blockIdx.x * blockDim.x + threadIdx.x;
    if (i < n) dinv[i] = rsqrtf((float)(cnt[i] + 1));
}

__global__ void edge_count(const int* __restrict__ dst, int* __restrict__ cnt, int E) {
    int i = blockIdx.x * blockDim.x + threadIdx.x;
    if (i < E) atomicAdd(&cnt[dst[i]], 1);
}

// ==================== prefix scan (exclusive) over cnt -> rp ====================
// chunk = 1024 elements per 256-thread block

__global__ __launch_bounds__(256) void scan_blocks(
    const int* __restrict__ cnt, int* __restrict__ rp, int* __restrict__ bsum, int n)
{
    __shared__ int ts[256];
    const int t = threadIdx.x;
    const int base = blockIdx.x * 1024 + t * 4;

    int v[4];
    #pragma unroll
    for (int i = 0; i < 4; ++i) v[i] = (base + i < n) ? cnt[base + i] : 0;
    int tsum = v[0] + v[1] + v[2] + v[3];

    ts[t] = tsum;
    __syncthreads();
    for (int off = 1; off < 256; off <<= 1) {
        int x = (t >= off) ? ts[t - off] : 0;
        __syncthreads();
        ts[t] += x;
        __syncthreads();
    }
    int run = ts[t] - tsum;   // exclusive prefix of this thread's chunk
    #pragma unroll
    for (int i = 0; i < 4; ++i) {
        if (base + i < n) rp[base + i] = run;
        run += v[i];
    }
    if (t == 255) bsum[blockIdx.x] = ts[255];
}

__global__ void scan_tops(int* __restrict__ bsum, int B) {
    if (threadIdx.x == 0 && blockIdx.x == 0) {
        int run = 0;
        for (int i = 0; i < B; ++i) { int v = bsum[i]; bsum[i] = run; run += v; }
    }
}

__global__ void scan_add(int* __restrict__ rp, const int* __restrict__ bsum, int n, int E) {
    int i = blockIdx.x * blockDim.x + threadIdx.x;
    if (i < n) rp[i] += bsum[i >> 10];
    if (i == 0) rp[n] = E;
}

// fill es: dst-sorted src indices
__global__ void edge_fill(const int* __restrict__ src, const int* __restrict__ dst,
                          const int* __restrict__ rp, int* __restrict__ cursor,
                          int* __restrict__ es, int E)
{
    int i = blockIdx.x * blockDim.x + threadIdx.x;
    if (i < E) {
        int d = dst[i];
        int pos = rp[d] + atomicAdd(&cursor[d], 1);
        es[pos] = src[i];
    }
}

// ==================== GEMM: H[v][m] = dinv[v] * sum_k relu?(X[v][k]) * W[k][m] ====================

__global__ __launch_bounds__(256) void gemm_scale(
    const float* __restrict__ X, const float* __restrict__ W,
    const float* __restrict__ dinv, float* __restrict__ H,
    int n, int K, int M, int relu_in)
{
    __shared__ float wS[128 * 64];   // max K*M = 32 KB
    __shared__ float xS[16 * 128];   // 16 node rows, max K=128

    const int tid = threadIdx.x;
    const int n0  = blockIdx.x * 16;

    for (int i = tid; i < K * M; i += 256) wS[i] = W[i];
    for (int i = tid; i < 16 * K; i += 256) {
        int r = i / K, c = i - r * K;
        int node = n0 + r;
        float v = 0.0f;
        if (node < n) v = X[(size_t)node * K + c];
        if (relu_in) v = fmaxf(v, 0.0f);
        xS[i] = v;
    }
    __syncthreads();

    const int col = tid & 63;
    const int nl  = tid >> 6;

    float acc[4] = {0.f, 0.f, 0.f, 0.f};
    if (col < M) {
        for (int k = 0; k < K; ++k) {
            float wv = wS[k * M + col];
            acc[0] += xS[(nl + 0)  * K + k] * wv;
            acc[1] += xS[(nl + 4)  * K + k] * wv;
            acc[2] += xS[(nl + 8)  * K + k] * wv;
            acc[3] += xS[(nl + 12) * K + k] * wv;
        }
        #pragma unroll
        for (int u = 0; u < 4; ++u) {
            int node = n0 + nl + 4 * u;
            if (node < n) H[(size_t)node * M + col] = acc[u] * dinv[node];
        }
    }
}

// ==================== gather aggregation ====================
// A[v][j] = b[j] + dinv[v] * ( H[v][j] + sum_{s in N(v)} H[s][j] )
// one wave per node; H already carries dinv[src].

__global__ __launch_bounds__(256) void gather_agg(
    const int* __restrict__ rp, const int* __restrict__ es,
    const float* __restrict__ H, const float* __restrict__ dinv,
    const float* __restrict__ b, float* __restrict__ A, int n, int M)
{
    int node = blockIdx.x * 4 + (threadIdx.x >> 6);
    int lane = threadIdx.x & 63;
    if (node >= n) return;

    int e0 = rp[node], e1 = rp[node + 1];

    float acc = 0.0f;
    if (lane < M) acc = H[(size_t)node * M + lane];   // self loop

    for (int base = e0; base < e1; base += 64) {
        int cnt = e1 - base; if (cnt > 64) cnt = 64;
        int si = (base + lane < e1) ? es[base + lane] : 0;
        for (int j = 0; j < cnt; ++j) {
            int s = __shfl(si, j, 64);
            if (lane < M) acc += H[(size_t)s * M + lane];
        }
    }

    if (lane < M) A[(size_t)node * M + lane] = acc * dinv[node] + b[lane];
}

// ==================== relu + log_softmax (wave per node, M<=64) ====================

__global__ __launch_bounds__(256) void logsoftmax_relu(
    const float* __restrict__ Z, float* __restrict__ out, int n, int M)
{
    int node = blockIdx.x * (blockDim.x >> 6) + (threadIdx.x >> 6);
    int lane = threadIdx.x & 63;
    if (node >= n) return;

    float z = -INFINITY;
    if (lane < M) z = fmaxf(Z[(size_t)node * M + lane], 0.0f);

    float m = z;
    #pragma unroll
    for (int o = 32; o >= 1; o >>= 1) m = fmaxf(m, __shfl_xor(m, o, 64));

    float e = (lane < M) ? expf(z - m) : 0.0f;
    float s = e;
    #pragma unroll
    for (int o = 32; o >= 1; o >>= 1) s += __shfl_xor(s, o, 64);

    if (lane < M) out[(size_t)node * M + lane] = z - m - logf(s);
}

// ==================== launch ====================

extern "C" void kernel_launch(void* const* d_in, const int* in_sizes, int n_in,
                              void* d_out, int out_size, void* d_ws, size_t ws_size,
                              hipStream_t stream)
{
    const float* x  = (const float*)d_in[0];
    const int*   ei = (const int*)  d_in[1];
    const float* W1 = (const float*)d_in[2];
    const float* b1 = (const float*)d_in[3];
    const float* W2 = (const float*)d_in[4];
    const float* b2 = (const float*)d_in[5];
    const float* W3 = (const float*)d_in[6];
    const float* b3 = (const float*)d_in[7];

    const int F_IN = 128, HID = 64, NCLS = 40;
    const int n = in_sizes[0] / F_IN;      // 100000
    const int E = in_sizes[1] / 2;         // 1600000
    const int* src = ei;
    const int* dst = ei + E;
    float* out = (float*)d_out;

    // ---- workspace layout (aligned to 256 B) ----
    auto align = [](size_t v) { return (v + 255) & ~(size_t)255; };
    char* w = (char*)d_ws;
    size_t off = 0;
    float* dinv = (float*)(w + off); off = align(off + (size_t)n * 4);
    float* H    = (float*)(w + off); off = align(off + (size_t)n * 64 * 4);
    float* A    = (float*)(w + off); off = align(off + (size_t)n * 64 * 4);
    int*   cnt  = (int*)  (w + off); off = align(off + (size_t)n * 4);
    int*   rp   = (int*)  (w + off); off = align(off + (size_t)(n + 1) * 4);
    int*   bsum = (int*)  (w + off); off = align(off + (size_t)1024 * 4);
    int*   es   = (int*)  (w + off); off = align(off + (size_t)E * 4);

    const int BLK = 256;
    auto cdiv = [](int a, int b) { return (a + b - 1) / b; };
    const int B = cdiv(n, 1024);

    // ---- CSR build (dst-sorted) + dinv ----
    zero_int   <<<cdiv(n, BLK), BLK, 0, stream>>>(cnt, n);
    edge_count <<<cdiv(E, BLK), BLK, 0, stream>>>(dst, cnt, E);
    make_dinv  <<<cdiv(n, BLK), BLK, 0, stream>>>(cnt, dinv, n);
    scan_blocks<<<B, BLK, 0, stream>>>(cnt, rp, bsum, n);
    scan_tops  <<<1, 64, 0, stream>>>(bsum, B);
    scan_add   <<<cdiv(n, BLK), BLK, 0, stream>>>(rp, bsum, n, E);
    zero_int   <<<cdiv(n, BLK), BLK, 0, stream>>>(cnt, n);   // reuse as cursor
    edge_fill  <<<cdiv(E, BLK), BLK, 0, stream>>>(src, dst, rp, cnt, es, E);

    // ---- layer 1: x(128) -> 64 ----
    gemm_scale <<<cdiv(n, 16), BLK, 0, stream>>>(x, W1, dinv, H, n, F_IN, HID, 0);
    gather_agg <<<cdiv(n, 4), BLK, 0, stream>>>(rp, es, H, dinv, b1, A, n, HID);

    // ---- layer 2: relu(A)(64) -> 64 ----
    gemm_scale <<<cdiv(n, 16), BLK, 0, stream>>>(A, W2, dinv, H, n, HID, HID, 1);
    gather_agg <<<cdiv(n, 4), BLK, 0, stream>>>(rp, es, H, dinv, b2, A, n, HID);

    // ---- layer 3: relu(A)(64) -> 40 ----
    gemm_scale <<<cdiv(n, 16), BLK, 0, stream>>>(A, W3, dinv, H, n, HID, NCLS, 1);
    gather_agg <<<cdiv(n, 4), BLK, 0, stream>>>(rp, es, H, dinv, b3, A, n, NCLS);

    // ---- relu + log_softmax ----
    logsoftmax_relu<<<cdiv(n, 4), BLK, 0, stream>>>(A, out, n, NCLS);
}

// Round 3
// 580.775 us; speedup vs baseline: 2.3723x; 1.3660x over previous
//
#include <hip/hip_runtime.h>
#include <math.h>

typedef _Float16 half8 __attribute__((ext_vector_type(8)));
typedef float float4v __attribute__((ext_vector_type(4)));

static __device__ __forceinline__ unsigned short f32_to_f16u(float f) {
    _Float16 h = (_Float16)f;
    return __builtin_bit_cast(unsigned short, h);
}
static __device__ __forceinline__ float f16u_to_f32(unsigned short u) {
    return (float)__builtin_bit_cast(_Float16, u);
}

// ==================== CSR build ====================

__global__ void zero_int(int* __restrict__ p, int n) {
    int i = blockIdx.x * blockDim.x + threadIdx.x;
    if (i < n) p[i] = 0;
}

__global__ void make_dinv(const int* __restrict__ cnt, float* __restrict__ dinv, int n) {
    int i = blockIdx.x * blockDim.x + threadIdx.x;
    if (i < n) dinv[i] = rsqrtf((float)(cnt[i] + 1));
}

__global__ void edge_count(const int* __restrict__ dst, int* __restrict__ cnt, int E) {
    int i = blockIdx.x * blockDim.x + threadIdx.x;
    if (i < E) atomicAdd(&cnt[dst[i]], 1);
}

__global__ __launch_bounds__(256) void scan_blocks(
    const int* __restrict__ cnt, int* __restrict__ rp, int* __restrict__ bsum, int n)
{
    __shared__ int ts[256];
    const int t = threadIdx.x;
    const int base = blockIdx.x * 1024 + t * 4;
    int v[4];
    #pragma unroll
    for (int i = 0; i < 4; ++i) v[i] = (base + i < n) ? cnt[base + i] : 0;
    int tsum = v[0] + v[1] + v[2] + v[3];
    ts[t] = tsum;
    __syncthreads();
    for (int off = 1; off < 256; off <<= 1) {
        int x = (t >= off) ? ts[t - off] : 0;
        __syncthreads();
        ts[t] += x;
        __syncthreads();
    }
    int run = ts[t] - tsum;
    #pragma unroll
    for (int i = 0; i < 4; ++i) {
        if (base + i < n) rp[base + i] = run;
        run += v[i];
    }
    if (t == 255) bsum[blockIdx.x] = ts[255];
}

__global__ void scan_tops(int* __restrict__ bsum, int B) {
    if (threadIdx.x == 0 && blockIdx.x == 0) {
        int run = 0;
        for (int i = 0; i < B; ++i) { int v = bsum[i]; bsum[i] = run; run += v; }
    }
}

__global__ void scan_add(int* __restrict__ rp, const int* __restrict__ bsum, int n, int E) {
    int i = blockIdx.x * blockDim.x + threadIdx.x;
    if (i < n) rp[i] += bsum[i >> 10];
    if (i == 0) rp[n] = E;
}

__global__ void edge_fill(const int* __restrict__ src, const int* __restrict__ dst,
                          const int* __restrict__ rp, int* __restrict__ cursor,
                          int* __restrict__ es, int E)
{
    int i = blockIdx.x * blockDim.x + threadIdx.x;
    if (i < E) {
        int d = dst[i];
        int pos = rp[d] + atomicAdd(&cursor[d], 1);
        es[pos] = src[i];
    }
}

// ==================== MFMA GEMM ====================
// H[v][m] = f16( dinv[v] * sum_k relu?(X[v][k]) * W[k][m] )
// Block: 256 thr = 4 waves, 64 nodes (16/wave). LDS holds A/B fragments in
// exact lane order so every compute access is a conflict-free ds_read_b128.
// A-frag (16x16x32 f16): A[m=lane&15][k=(lane>>4)*8+j], j=0..7
// B-frag:                B[k=(lane>>4)*8+j][n=lane&15]
// C/D:                   col=lane&15, row=(lane>>4)*4+reg

__global__ __launch_bounds__(256) void gemm_mfma(
    const void* __restrict__ Xin, const float* __restrict__ W,
    const float* __restrict__ dinv, unsigned short* __restrict__ H,
    int n, int K, int Mout, int in_f32, int relu_in)
{
    __shared__ __align__(16) unsigned short lds[16384];  // 32 KB max
    const int KS  = K >> 5;             // k-steps of 32
    const int NT  = (Mout + 15) >> 4;   // 16-col tiles
    const int NTC = NT << 4;
    const int tid = threadIdx.x;
    const int n0  = blockIdx.x * 64;
    unsigned short* ldsA = lds;                  // 4*KS*512 ushorts
    unsigned short* ldsB = lds + 4 * KS * 512;   // NT*KS*512 ushorts

    // ---- stage X/A tile (64 rows x K) as A-fragments ----
    {
        const int rl = tid >> 3;      // 0..31
        const int kl = tid & 7;
        for (int rb = 0; rb < 64; rb += 32) {
            int r = rl + rb;
            int node = n0 + r;
            int t = r >> 4, m = r & 15;
            for (int kq8 = 0; kq8 < (K >> 2); kq8 += 8) {
                int k0 = (kl + kq8) << 2;       // multiple of 4
                unsigned short h[4] = {0, 0, 0, 0};
                if (node < n) {
                    if (in_f32) {
                        const float* xp = (const float*)Xin + (size_t)node * K + k0;
                        float4v v = *(const float4v*)xp;
                        #pragma unroll
                        for (int i = 0; i < 4; ++i) {
                            float f = v[i];
                            if (relu_in) f = fmaxf(f, 0.0f);
                            h[i] = f32_to_f16u(f);
                        }
                    } else {
                        const unsigned int* ap =
                            (const unsigned int*)Xin + (((size_t)node * K + k0) >> 1);
                        uint2 v = *(const uint2*)ap;
                        h[0] = (unsigned short)(v.x & 0xffff);
                        h[1] = (unsigned short)(v.x >> 16);
                        h[2] = (unsigned short)(v.y & 0xffff);
                        h[3] = (unsigned short)(v.y >> 16);
                        if (relu_in) {
                            #pragma unroll
                            for (int i = 0; i < 4; ++i)
                                if (h[i] & 0x8000) h[i] = 0;   // f16 relu
                        }
                    }
                }
                int s = k0 >> 5, q = (k0 >> 3) & 3, j0 = k0 & 7;
                int lane = (q << 4) | m;
                unsigned short* p = &ldsA[((t * KS + s) << 9) + (lane << 3) + j0];
                unsigned int lo = (unsigned int)h[0] | ((unsigned int)h[1] << 16);
                unsigned int hi = (unsigned int)h[2] | ((unsigned int)h[3] << 16);
                *(uint2*)p = make_uint2(lo, hi);   // 8 B aligned
            }
        }
    }

    // ---- stage W (K x Mout, zero-pad cols to NTC) as B-fragments ----
    for (int i = tid; i < K * NTC; i += 256) {
        int k  = i / NTC;
        int nn = i - k * NTC;
        unsigned short hv = 0;
        if (nn < Mout) hv = f32_to_f16u(W[(size_t)k * Mout + nn]);
        int s = k >> 5, q = (k >> 3) & 3, j = k & 7;
        int u = nn >> 4;
        int lane = (q << 4) | (nn & 15);
        ldsB[((u * KS + s) << 9) + (lane << 3) + j] = hv;
    }

    __syncthreads();

    // ---- MFMA ----
    const int wv   = tid >> 6;
    const int lane = tid & 63;
    float4v acc[4];
    #pragma unroll
    for (int u = 0; u < 4; ++u) acc[u] = (float4v){0.f, 0.f, 0.f, 0.f};

    for (int s = 0; s < KS; ++s) {
        half8 a = *(const half8*)&ldsA[((wv * KS + s) << 9) + (lane << 3)];
        for (int u = 0; u < NT; ++u) {
            half8 b = *(const half8*)&ldsB[((u * KS + s) << 9) + (lane << 3)];
            acc[u] = __builtin_amdgcn_mfma_f32_16x16x32_f16(a, b, acc[u], 0, 0, 0);
        }
    }

    // ---- epilogue: scale by dinv, store f16 ----
    const int mcol = lane & 15;
    const int quad = lane >> 4;
    #pragma unroll
    for (int reg = 0; reg < 4; ++reg) {
        int node = n0 + (wv << 4) + (quad << 2) + reg;
        if (node >= n) continue;
        float dv = dinv[node];
        for (int u = 0; u < NT; ++u) {
            int col = (u << 4) + mcol;
            if (col < Mout)
                H[(size_t)node * Mout + col] = f32_to_f16u(acc[u][reg] * dv);
        }
    }
}

// ==================== gather aggregation (f16 H/A) ====================
// A[v] = f16( b + dinv[v] * (H[v] + sum_{s in N(v)} H[s]) )
// one wave per node; lanes 0-31 & 32-63 each handle a col-pair for alternate
// edges (2 edges in flight per wave-load), cross-half reduce at the end.
// P = Mcols/2 (dwords per row).

__global__ __launch_bounds__(256) void gather_agg_f16(
    const int* __restrict__ rp, const int* __restrict__ es,
    const unsigned short* __restrict__ H, const float* __restrict__ dinv,
    const float* __restrict__ b, unsigned short* __restrict__ A, int n, int P)
{
    int node = blockIdx.x * 4 + (threadIdx.x >> 6);
    int lane = threadIdx.x & 63;
    if (node >= n) return;
    int c = lane & 31, half = lane >> 5;
    bool act = c < P;
    const unsigned int* H2 = (const unsigned int*)H;
    int e0 = rp[node], e1 = rp[node + 1];

    float a0 = 0.f, a1 = 0.f;
    if (act && half == 0) {                       // self loop
        unsigned int u = H2[(size_t)node * P + c];
        a0 = f16u_to_f32((unsigned short)(u & 0xffff));
        a1 = f16u_to_f32((unsigned short)(u >> 16));
    }

    for (int base = e0; base < e1; base += 64) {
        int cnt = e1 - base; if (cnt > 64) cnt = 64;
        int idx = base + lane; if (idx >= e1) idx = e1 - 1;
        int si = es[idx];
        for (int j = 0; j < cnt; j += 2) {
            int jj = j + half;
            int s = __shfl(si, jj, 64);
            if (jj < cnt && act) {
                unsigned int u = H2[(size_t)s * P + c];
                a0 += f16u_to_f32((unsigned short)(u & 0xffff));
                a1 += f16u_to_f32((unsigned short)(u >> 16));
            }
        }
    }

    a0 += __shfl_xor(a0, 32, 64);
    a1 += __shfl_xor(a1, 32, 64);

    if (act && half == 0) {
        float dv = dinv[node];
        float v0 = a0 * dv + b[2 * c];
        float v1 = a1 * dv + b[2 * c + 1];
        ((unsigned int*)A)[(size_t)node * P + c] =
            (unsigned int)f32_to_f16u(v0) | ((unsigned int)f32_to_f16u(v1) << 16);
    }
}

// ==================== relu + log_softmax (f16 in, f32 out) ====================

__global__ __launch_bounds__(256) void logsoftmax_f16(
    const unsigned short* __restrict__ Z, float* __restrict__ out, int n, int M)
{
    int node = blockIdx.x * 4 + (threadIdx.x >> 6);
    int lane = threadIdx.x & 63;
    if (node >= n) return;

    float z = -INFINITY;
    if (lane < M) z = fmaxf(f16u_to_f32(Z[(size_t)node * M + lane]), 0.0f);

    float m = z;
    #pragma unroll
    for (int o = 32; o >= 1; o >>= 1) m = fmaxf(m, __shfl_xor(m, o, 64));

    float e = (lane < M) ? expf(z - m) : 0.0f;
    float s = e;
    #pragma unroll
    for (int o = 32; o >= 1; o >>= 1) s += __shfl_xor(s, o, 64);

    if (lane < M) out[(size_t)node * M + lane] = z - m - logf(s);
}

// ==================== launch ====================

extern "C" void kernel_launch(void* const* d_in, const int* in_sizes, int n_in,
                              void* d_out, int out_size, void* d_ws, size_t ws_size,
                              hipStream_t stream)
{
    const float* x  = (const float*)d_in[0];
    const int*   ei = (const int*)  d_in[1];
    const float* W1 = (const float*)d_in[2];
    const float* b1 = (const float*)d_in[3];
    const float* W2 = (const float*)d_in[4];
    const float* b2 = (const float*)d_in[5];
    const float* W3 = (const float*)d_in[6];
    const float* b3 = (const float*)d_in[7];

    const int F_IN = 128, HID = 64, NCLS = 40;
    const int n = in_sizes[0] / F_IN;      // 100000
    const int E = in_sizes[1] / 2;         // 1600000
    const int* src = ei;
    const int* dst = ei + E;
    float* out = (float*)d_out;

    // ---- workspace layout ----
    auto align = [](size_t v) { return (v + 255) & ~(size_t)255; };
    char* w = (char*)d_ws;
    size_t off = 0;
    float*          dinv = (float*)(w + off);          off = align(off + (size_t)n * 4);
    unsigned short* H    = (unsigned short*)(w + off); off = align(off + (size_t)n * 64 * 2);
    unsigned short* A    = (unsigned short*)(w + off); off = align(off + (size_t)n * 64 * 2);
    int*            cnt  = (int*)(w + off);            off = align(off + (size_t)n * 4);
    int*            rp   = (int*)(w + off);            off = align(off + (size_t)(n + 1) * 4);
    int*            bsum = (int*)(w + off);            off = align(off + (size_t)1024 * 4);
    int*            es   = (int*)(w + off);            off = align(off + (size_t)E * 4);

    const int BLK = 256;
    auto cdiv = [](int a, int b) { return (a + b - 1) / b; };
    const int B = cdiv(n, 1024);

    // ---- CSR build (dst-sorted) + dinv ----
    zero_int   <<<cdiv(n, BLK), BLK, 0, stream>>>(cnt, n);
    edge_count <<<cdiv(E, BLK), BLK, 0, stream>>>(dst, cnt, E);
    make_dinv  <<<cdiv(n, BLK), BLK, 0, stream>>>(cnt, dinv, n);
    scan_blocks<<<B, BLK, 0, stream>>>(cnt, rp, bsum, n);
    scan_tops  <<<1, 64, 0, stream>>>(bsum, B);
    scan_add   <<<cdiv(n, BLK), BLK, 0, stream>>>(rp, bsum, n, E);
    zero_int   <<<cdiv(n, BLK), BLK, 0, stream>>>(cnt, n);   // reuse as cursor
    edge_fill  <<<cdiv(E, BLK), BLK, 0, stream>>>(src, dst, rp, cnt, es, E);

    const int GB = cdiv(n, 64);

    // ---- layer 1: x(f32,128) -> H(64) ----
    gemm_mfma     <<<GB, BLK, 0, stream>>>(x, W1, dinv, H, n, F_IN, HID, 1, 0);
    gather_agg_f16<<<cdiv(n, 4), BLK, 0, stream>>>(rp, es, H, dinv, b1, A, n, HID / 2);

    // ---- layer 2: relu(A)(f16,64) -> H(64) ----
    gemm_mfma     <<<GB, BLK, 0, stream>>>(A, W2, dinv, H, n, HID, HID, 0, 1);
    gather_agg_f16<<<cdiv(n, 4), BLK, 0, stream>>>(rp, es, H, dinv, b2, A, n, HID / 2);

    // ---- layer 3: relu(A)(f16,64) -> H(40) ----
    gemm_mfma     <<<GB, BLK, 0, stream>>>(A, W3, dinv, H, n, HID, NCLS, 0, 1);
    gather_agg_f16<<<cdiv(n, 4), BLK, 0, stream>>>(rp, es, H, dinv, b3, A, n, NCLS / 2);

    // ---- relu + log_softmax ----
    logsoftmax_f16<<<cdiv(n, 4), BLK, 0, stream>>>(A, out, n, NCLS);
}

// Round 4
// 486.793 us; speedup vs baseline: 2.8303x; 1.1931x over previous
//
#include <hip/hip_runtime.h>
#include <math.h>

typedef _Float16 half8 __attribute__((ext_vector_type(8)));
typedef float float4v __attribute__((ext_vector_type(4)));

static __device__ __forceinline__ unsigned short f32_to_f16u(float f) {
    _Float16 h = (_Float16)f;
    return __builtin_bit_cast(unsigned short, h);
}
static __device__ __forceinline__ float f16u_to_f32(unsigned short u) {
    return (float)__builtin_bit_cast(_Float16, u);
}

// ==================== bucketed CSR build ====================
// Buckets of 256 nodes by dst>>8. NB = ceil(n/256) must be <= 512.

__global__ void zero_int(int* __restrict__ p, int n) {
    int i = blockIdx.x * blockDim.x + threadIdx.x;
    if (i < n) p[i] = 0;
}

// Pass A: per-block LDS histogram of dst>>8, flush to global bucket_cnt.
__global__ __launch_bounds__(256) void hist_bucket(
    const int* __restrict__ dst, int* __restrict__ bcnt, int E, int NB)
{
    __shared__ int h[512];
    const int tid = threadIdx.x;
    h[tid] = 0; h[tid + 256] = 0;
    __syncthreads();
    const int base = blockIdx.x * 2048 + tid;
    #pragma unroll
    for (int k = 0; k < 8; ++k) {
        int i = base + k * 256;
        if (i < E) atomicAdd(&h[dst[i] >> 8], 1);
    }
    __syncthreads();
    for (int j = tid; j < NB; j += 256)
        if (h[j]) atomicAdd(&bcnt[j], h[j]);
}

// single-block exclusive scan over NB buckets -> boff, bcur; also rp[n]=E
__global__ __launch_bounds__(512) void scan_nb(
    const int* __restrict__ bcnt, int* __restrict__ boff, int* __restrict__ bcur,
    int* __restrict__ rp, int NB, int n, int E)
{
    __shared__ int s[512];
    const int tid = threadIdx.x;
    int v = (tid < NB) ? bcnt[tid] : 0;
    s[tid] = v;
    __syncthreads();
    for (int off = 1; off < 512; off <<= 1) {
        int x = (tid >= off) ? s[tid - off] : 0;
        __syncthreads();
        s[tid] += x;
        __syncthreads();
    }
    int excl = s[tid] - v;
    if (tid < NB) { boff[tid] = excl; bcur[tid] = excl; }
    if (tid == NB - 1) boff[NB] = excl + v;
    if (tid == 0) rp[n] = E;
}

// Pass B: scatter packed (src<<8 | dst&255) into bucket-contiguous regions.
// Block-aggregated reservations: one global atomic per (block,bucket).
__global__ __launch_bounds__(256) void bin_edges(
    const int* __restrict__ src, const int* __restrict__ dst,
    int* __restrict__ bcur, unsigned int* __restrict__ bint, int E, int NB)
{
    __shared__ int h[512];
    __shared__ int rbase[512];
    const int tid = threadIdx.x;
    h[tid] = 0; h[tid + 256] = 0;
    __syncthreads();
    const int eb = blockIdx.x * 2048 + tid;
    int d[8], sr[8];
    #pragma unroll
    for (int k = 0; k < 8; ++k) {
        int i = eb + k * 256;
        if (i < E) {
            d[k] = dst[i]; sr[k] = src[i];
            atomicAdd(&h[d[k] >> 8], 1);
        } else d[k] = -1;
    }
    __syncthreads();
    for (int j = tid; j < NB; j += 256) {
        int c = h[j];
        rbase[j] = c ? atomicAdd(&bcur[j], c) : 0;
        h[j] = 0;   // reuse as local cursor
    }
    __syncthreads();
    #pragma unroll
    for (int k = 0; k < 8; ++k) {
        if (d[k] >= 0) {
            int bkt = d[k] >> 8;
            int pos = rbase[bkt] + atomicAdd(&h[bkt], 1);
            bint[pos] = ((unsigned int)sr[k] << 8) | (unsigned int)(d[k] & 255);
        }
    }
}

// Pass C: one block per bucket: count per node (LDS), scan, write rp/dinv/es.
__global__ __launch_bounds__(256) void build_csr(
    const unsigned int* __restrict__ bint, const int* __restrict__ boff,
    int* __restrict__ rp, float* __restrict__ dinv, int* __restrict__ es, int n)
{
    __shared__ int cnt[256];
    __shared__ int sc[256];
    __shared__ int cur[256];
    const int b = blockIdx.x, tid = threadIdx.x;
    const int e0 = boff[b], e1 = boff[b + 1];

    cnt[tid] = 0;
    __syncthreads();
    for (int i = e0 + tid; i < e1; i += 256)
        atomicAdd(&cnt[bint[i] & 255], 1);
    __syncthreads();

    int v = cnt[tid];
    sc[tid] = v;
    __syncthreads();
    for (int off = 1; off < 256; off <<= 1) {
        int x = (tid >= off) ? sc[tid - off] : 0;
        __syncthreads();
        sc[tid] += x;
        __syncthreads();
    }
    int excl = sc[tid] - v;
    int node = (b << 8) + tid;
    if (node < n) {
        rp[node]   = e0 + excl;
        dinv[node] = rsqrtf((float)(v + 1));
    }
    cur[tid] = e0 + excl;
    __syncthreads();

    for (int i = e0 + tid; i < e1; i += 256) {
        unsigned int p = bint[i];
        int pos = atomicAdd(&cur[p & 255], 1);
        es[pos] = (int)(p >> 8);
    }
}

// ==================== MFMA GEMM ====================
// H[v][m] = f16( dinv[v] * sum_k relu?(X[v][k]) * W[k][m] ), H row stride 64
// (cols >= Mout zeroed). Fragment layouts as in round 3.

__global__ __launch_bounds__(256) void gemm_mfma(
    const void* __restrict__ Xin, const float* __restrict__ W,
    const float* __restrict__ dinv, unsigned short* __restrict__ H,
    int n, int K, int Mout, int in_f32, int relu_in)
{
    __shared__ __align__(16) unsigned short lds[16384];  // 32 KB max
    const int KS  = K >> 5;
    const int NT  = (Mout + 15) >> 4;
    const int NTC = NT << 4;
    const int tid = threadIdx.x;
    const int n0  = blockIdx.x * 64;
    unsigned short* ldsA = lds;
    unsigned short* ldsB = lds + 4 * KS * 512;

    // ---- stage X/A tile (64 rows x K) as A-fragments ----
    {
        const int rl = tid >> 3;
        const int kl = tid & 7;
        for (int rb = 0; rb < 64; rb += 32) {
            int r = rl + rb;
            int node = n0 + r;
            int t = r >> 4, m = r & 15;
            for (int kq8 = 0; kq8 < (K >> 2); kq8 += 8) {
                int k0 = (kl + kq8) << 2;
                unsigned short h[4] = {0, 0, 0, 0};
                if (node < n) {
                    if (in_f32) {
                        const float* xp = (const float*)Xin + (size_t)node * K + k0;
                        float4v v = *(const float4v*)xp;
                        #pragma unroll
                        for (int i = 0; i < 4; ++i) {
                            float f = v[i];
                            if (relu_in) f = fmaxf(f, 0.0f);
                            h[i] = f32_to_f16u(f);
                        }
                    } else {
                        const unsigned int* ap =
                            (const unsigned int*)Xin + (((size_t)node * K + k0) >> 1);
                        uint2 v = *(const uint2*)ap;
                        h[0] = (unsigned short)(v.x & 0xffff);
                        h[1] = (unsigned short)(v.x >> 16);
                        h[2] = (unsigned short)(v.y & 0xffff);
                        h[3] = (unsigned short)(v.y >> 16);
                        if (relu_in) {
                            #pragma unroll
                            for (int i = 0; i < 4; ++i)
                                if (h[i] & 0x8000) h[i] = 0;
                        }
                    }
                }
                int s = k0 >> 5, q = (k0 >> 3) & 3, j0 = k0 & 7;
                int lane = (q << 4) | m;
                unsigned short* p = &ldsA[((t * KS + s) << 9) + (lane << 3) + j0];
                unsigned int lo = (unsigned int)h[0] | ((unsigned int)h[1] << 16);
                unsigned int hi = (unsigned int)h[2] | ((unsigned int)h[3] << 16);
                *(uint2*)p = make_uint2(lo, hi);
            }
        }
    }

    // ---- stage W as B-fragments (zero-pad cols to NTC) ----
    for (int i = tid; i < K * NTC; i += 256) {
        int k  = i / NTC;
        int nn = i - k * NTC;
        unsigned short hv = 0;
        if (nn < Mout) hv = f32_to_f16u(W[(size_t)k * Mout + nn]);
        int s = k >> 5, q = (k >> 3) & 3, j = k & 7;
        int u = nn >> 4;
        int lane = (q << 4) | (nn & 15);
        ldsB[((u * KS + s) << 9) + (lane << 3) + j] = hv;
    }

    __syncthreads();

    const int wv   = tid >> 6;
    const int lane = tid & 63;
    float4v acc[4];
    #pragma unroll
    for (int u = 0; u < 4; ++u) acc[u] = (float4v){0.f, 0.f, 0.f, 0.f};

    for (int s = 0; s < KS; ++s) {
        half8 a = *(const half8*)&ldsA[((wv * KS + s) << 9) + (lane << 3)];
        for (int u = 0; u < NT; ++u) {
            half8 b = *(const half8*)&ldsB[((u * KS + s) << 9) + (lane << 3)];
            acc[u] = __builtin_amdgcn_mfma_f32_16x16x32_f16(a, b, acc[u], 0, 0, 0);
        }
    }

    // ---- epilogue: scale by dinv, store f16 row of stride 64 (pad zeros) ----
    const int mcol = lane & 15;
    const int quad = lane >> 4;
    #pragma unroll
    for (int reg = 0; reg < 4; ++reg) {
        int node = n0 + (wv << 4) + (quad << 2) + reg;
        if (node >= n) continue;
        float dv = dinv[node];
        #pragma unroll
        for (int u = 0; u < 4; ++u) {
            int col = (u << 4) + mcol;
            float val = (u < NT) ? acc[u][reg] * dv : 0.0f;
            H[(size_t)node * 64 + col] = f32_to_f16u(val);
        }
    }
}

// ==================== gather aggregation: 8 edges/wave-instruction ====================
// Rows are 64 f16 = 128 B. 8 lanes x 16 B cover a row; 8 slots = 8 edges.
// A[v] = f16( b + dinv[v] * (H[v] + sum_{s in N(v)} H[s]) ), cols>=Mout -> 0.

__global__ __launch_bounds__(256) void gather8(
    const int* __restrict__ rp, const int* __restrict__ es,
    const unsigned short* __restrict__ H, const float* __restrict__ dinv,
    const float* __restrict__ bias, unsigned short* __restrict__ A,
    int n, int Mout)
{
    int node = blockIdx.x * 4 + (threadIdx.x >> 6);
    int lane = threadIdx.x & 63;
    if (node >= n) return;
    const int slot = lane >> 3;
    const int c8   = lane & 7;
    const uint4* H4 = (const uint4*)H;   // 8 uint4 per row

    float acc[8] = {0.f, 0.f, 0.f, 0.f, 0.f, 0.f, 0.f, 0.f};

    if (slot == 0) {   // self loop
        uint4 u = H4[(size_t)node * 8 + c8];
        acc[0] = f16u_to_f32((unsigned short)(u.x & 0xffff));
        acc[1] = f16u_to_f32((unsigned short)(u.x >> 16));
        acc[2] = f16u_to_f32((unsigned short)(u.y & 0xffff));
        acc[3] = f16u_to_f32((unsigned short)(u.y >> 16));
        acc[4] = f16u_to_f32((unsigned short)(u.z & 0xffff));
        acc[5] = f16u_to_f32((unsigned short)(u.z >> 16));
        acc[6] = f16u_to_f32((unsigned short)(u.w & 0xffff));
        acc[7] = f16u_to_f32((unsigned short)(u.w >> 16));
    }

    const int e0 = rp[node], e1 = rp[node + 1];
    for (int base = e0; base < e1; base += 8) {
        int idx = base + slot;
        if (idx < e1) {
            int s = es[idx];
            uint4 u = H4[(size_t)s * 8 + c8];
            acc[0] += f16u_to_f32((unsigned short)(u.x & 0xffff));
            acc[1] += f16u_to_f32((unsigned short)(u.x >> 16));
            acc[2] += f16u_to_f32((unsigned short)(u.y & 0xffff));
            acc[3] += f16u_to_f32((unsigned short)(u.y >> 16));
            acc[4] += f16u_to_f32((unsigned short)(u.z & 0xffff));
            acc[5] += f16u_to_f32((unsigned short)(u.z >> 16));
            acc[6] += f16u_to_f32((unsigned short)(u.w & 0xffff));
            acc[7] += f16u_to_f32((unsigned short)(u.w >> 16));
        }
    }

    #pragma unroll
    for (int i = 0; i < 8; ++i) {
        acc[i] += __shfl_xor(acc[i], 8, 64);
        acc[i] += __shfl_xor(acc[i], 16, 64);
        acc[i] += __shfl_xor(acc[i], 32, 64);
    }

    if (slot == 0) {
        float dv = dinv[node];
        unsigned short o[8];
        #pragma unroll
        for (int i = 0; i < 8; ++i) {
            int col = (c8 << 3) + i;
            float v = (col < Mout) ? acc[i] * dv + bias[col] : 0.0f;
            o[i] = f32_to_f16u(v);
        }
        uint4 w;
        w.x = (unsigned int)o[0] | ((unsigned int)o[1] << 16);
        w.y = (unsigned int)o[2] | ((unsigned int)o[3] << 16);
        w.z = (unsigned int)o[4] | ((unsigned int)o[5] << 16);
        w.w = (unsigned int)o[6] | ((unsigned int)o[7] << 16);
        ((uint4*)A)[(size_t)node * 8 + c8] = w;
    }
}

// ==================== relu + log_softmax (f16 in stride 64, f32 out) ====================

__global__ __launch_bounds__(256) void logsoftmax_f16(
    const unsigned short* __restrict__ Z, float* __restrict__ out, int n, int M)
{
    int node = blockIdx.x * 4 + (threadIdx.x >> 6);
    int lane = threadIdx.x & 63;
    if (node >= n) return;

    float z = -INFINITY;
    if (lane < M) z = fmaxf(f16u_to_f32(Z[(size_t)node * 64 + lane]), 0.0f);

    float m = z;
    #pragma unroll
    for (int o = 32; o >= 1; o >>= 1) m = fmaxf(m, __shfl_xor(m, o, 64));

    float e = (lane < M) ? expf(z - m) : 0.0f;
    float s = e;
    #pragma unroll
    for (int o = 32; o >= 1; o >>= 1) s += __shfl_xor(s, o, 64);

    if (lane < M) out[(size_t)node * M + lane] = z - m - logf(s);
}

// ==================== launch ====================

extern "C" void kernel_launch(void* const* d_in, const int* in_sizes, int n_in,
                              void* d_out, int out_size, void* d_ws, size_t ws_size,
                              hipStream_t stream)
{
    const float* x  = (const float*)d_in[0];
    const int*   ei = (const int*)  d_in[1];
    const float* W1 = (const float*)d_in[2];
    const float* b1 = (const float*)d_in[3];
    const float* W2 = (const float*)d_in[4];
    const float* b2 = (const float*)d_in[5];
    const float* W3 = (const float*)d_in[6];
    const float* b3 = (const float*)d_in[7];

    const int F_IN = 128, HID = 64, NCLS = 40;
    const int n = in_sizes[0] / F_IN;      // 100000
    const int E = in_sizes[1] / 2;         // 1600000
    const int* src = ei;
    const int* dst = ei + E;
    float* out = (float*)d_out;

    const int NB = (n + 255) >> 8;         // 391 buckets (<= 512 required)

    // ---- workspace layout ----
    auto align = [](size_t v) { return (v + 255) & ~(size_t)255; };
    char* w = (char*)d_ws;
    size_t off = 0;
    float*          dinv = (float*)(w + off);          off = align(off + (size_t)n * 4);
    unsigned short* H    = (unsigned short*)(w + off); off = align(off + (size_t)n * 64 * 2);
    unsigned short* A    = (unsigned short*)(w + off); off = align(off + (size_t)n * 64 * 2);
    int*            rp   = (int*)(w + off);            off = align(off + (size_t)(n + 1) * 4);
    int*            es   = (int*)(w + off);            off = align(off + (size_t)E * 4);
    unsigned int*   bint = (unsigned int*)(w + off);   off = align(off + (size_t)E * 4);
    int*            bcnt = (int*)(w + off);            off = align(off + (size_t)512 * 4);
    int*            boff = (int*)(w + off);            off = align(off + (size_t)513 * 4);
    int*            bcur = (int*)(w + off);            off = align(off + (size_t)512 * 4);

    const int BLK = 256;
    auto cdiv = [](int a, int b) { return (a + b - 1) / b; };
    const int EB = cdiv(E, 2048);

    // ---- CSR build (bucketed counting sort) ----
    zero_int   <<<cdiv(NB, BLK), BLK, 0, stream>>>(bcnt, NB);
    hist_bucket<<<EB, BLK, 0, stream>>>(dst, bcnt, E, NB);
    scan_nb    <<<1, 512, 0, stream>>>(bcnt, boff, bcur, rp, NB, n, E);
    bin_edges  <<<EB, BLK, 0, stream>>>(src, dst, bcur, bint, E, NB);
    build_csr  <<<NB, BLK, 0, stream>>>(bint, boff, rp, dinv, es, n);

    const int GB = cdiv(n, 64);

    // ---- layer 1: x(f32,128) -> H(64) ----
    gemm_mfma<<<GB, BLK, 0, stream>>>(x, W1, dinv, H, n, F_IN, HID, 1, 0);
    gather8  <<<cdiv(n, 4), BLK, 0, stream>>>(rp, es, H, dinv, b1, A, n, HID);

    // ---- layer 2: relu(A)(f16,64) -> H(64) ----
    gemm_mfma<<<GB, BLK, 0, stream>>>(A, W2, dinv, H, n, HID, HID, 0, 1);
    gather8  <<<cdiv(n, 4), BLK, 0, stream>>>(rp, es, H, dinv, b2, A, n, HID);

    // ---- layer 3: relu(A)(f16,64) -> H(40 in 64-stride rows) ----
    gemm_mfma<<<GB, BLK, 0, stream>>>(A, W3, dinv, H, n, HID, NCLS, 0, 1);
    gather8  <<<cdiv(n, 4), BLK, 0, stream>>>(rp, es, H, dinv, b3, A, n, NCLS);

    // ---- relu + log_softmax ----
    logsoftmax_f16<<<cdiv(n, 4), BLK, 0, stream>>>(A, out, n, NCLS);
}

// Round 5
// 332.385 us; speedup vs baseline: 4.1452x; 1.4645x over previous
//
#include <hip/hip_runtime.h>
#include <math.h>

typedef _Float16 half2v __attribute__((ext_vector_type(2)));
typedef _Float16 half8  __attribute__((ext_vector_type(8)));
typedef float    float4v __attribute__((ext_vector_type(4)));

static __device__ __forceinline__ unsigned short f32_to_f16u(float f) {
    _Float16 h = (_Float16)f;
    return __builtin_bit_cast(unsigned short, h);
}
static __device__ __forceinline__ float fdot2u(unsigned int pair, half2v m, float acc) {
    return __builtin_amdgcn_fdot2(__builtin_bit_cast(half2v, pair), m, acc, false);
}

// ==================== bucketed CSR build (as R4) ====================

__global__ void zero_int(int* __restrict__ p, int n) {
    int i = blockIdx.x * blockDim.x + threadIdx.x;
    if (i < n) p[i] = 0;
}

__global__ __launch_bounds__(256) void hist_bucket(
    const int* __restrict__ dst, int* __restrict__ bcnt, int E, int NB)
{
    __shared__ int h[512];
    const int tid = threadIdx.x;
    h[tid] = 0; h[tid + 256] = 0;
    __syncthreads();
    const int base = blockIdx.x * 2048 + tid;
    #pragma unroll
    for (int k = 0; k < 8; ++k) {
        int i = base + k * 256;
        if (i < E) atomicAdd(&h[dst[i] >> 8], 1);
    }
    __syncthreads();
    for (int j = tid; j < NB; j += 256)
        if (h[j]) atomicAdd(&bcnt[j], h[j]);
}

__global__ __launch_bounds__(512) void scan_nb(
    const int* __restrict__ bcnt, int* __restrict__ boff, int* __restrict__ bcur,
    int* __restrict__ rp, int NB, int n, int E)
{
    __shared__ int s[512];
    const int tid = threadIdx.x;
    int v = (tid < NB) ? bcnt[tid] : 0;
    s[tid] = v;
    __syncthreads();
    for (int off = 1; off < 512; off <<= 1) {
        int x = (tid >= off) ? s[tid - off] : 0;
        __syncthreads();
        s[tid] += x;
        __syncthreads();
    }
    int excl = s[tid] - v;
    if (tid < NB) { boff[tid] = excl; bcur[tid] = excl; }
    if (tid == NB - 1) boff[NB] = excl + v;
    if (tid == 0) rp[n] = E;
}

__global__ __launch_bounds__(256) void bin_edges(
    const int* __restrict__ src, const int* __restrict__ dst,
    int* __restrict__ bcur, unsigned int* __restrict__ bint, int E, int NB)
{
    __shared__ int h[512];
    __shared__ int rbase[512];
    const int tid = threadIdx.x;
    h[tid] = 0; h[tid + 256] = 0;
    __syncthreads();
    const int eb = blockIdx.x * 2048 + tid;
    int d[8], sr[8];
    #pragma unroll
    for (int k = 0; k < 8; ++k) {
        int i = eb + k * 256;
        if (i < E) {
            d[k] = dst[i]; sr[k] = src[i];
            atomicAdd(&h[d[k] >> 8], 1);
        } else d[k] = -1;
    }
    __syncthreads();
    for (int j = tid; j < NB; j += 256) {
        int c = h[j];
        rbase[j] = c ? atomicAdd(&bcur[j], c) : 0;
        h[j] = 0;
    }
    __syncthreads();
    #pragma unroll
    for (int k = 0; k < 8; ++k) {
        if (d[k] >= 0) {
            int bkt = d[k] >> 8;
            int pos = rbase[bkt] + atomicAdd(&h[bkt], 1);
            bint[pos] = ((unsigned int)sr[k] << 8) | (unsigned int)(d[k] & 255);
        }
    }
}

__global__ __launch_bounds__(256) void build_csr(
    const unsigned int* __restrict__ bint, const int* __restrict__ boff,
    int* __restrict__ rp, float* __restrict__ dinv, int* __restrict__ es, int n)
{
    __shared__ int cnt[256];
    __shared__ int sc[256];
    __shared__ int cur[256];
    const int b = blockIdx.x, tid = threadIdx.x;
    const int e0 = boff[b], e1 = boff[b + 1];

    cnt[tid] = 0;
    __syncthreads();
    for (int i = e0 + tid; i < e1; i += 256)
        atomicAdd(&cnt[bint[i] & 255], 1);
    __syncthreads();

    int v = cnt[tid];
    sc[tid] = v;
    __syncthreads();
    for (int off = 1; off < 256; off <<= 1) {
        int x = (tid >= off) ? sc[tid - off] : 0;
        __syncthreads();
        sc[tid] += x;
        __syncthreads();
    }
    int excl = sc[tid] - v;
    int node = (b << 8) + tid;
    if (node < n) {
        rp[node]   = e0 + excl;
        dinv[node] = rsqrtf((float)(v + 1));
    }
    cur[tid] = e0 + excl;
    __syncthreads();

    for (int i = e0 + tid; i < e1; i += 256) {
        unsigned int p = bint[i];
        int pos = atomicAdd(&cur[p & 255], 1);
        es[pos] = (int)(p >> 8);
    }
}

// ==================== W -> B-fragment preformat (once) ====================
// B-frag layout: frag (u,s) at Wf[((u*KS+s)<<9) + (lane<<3) + j],
// lane=(q<<4)|(col&15), k = s*32 + q*8 + j.

__global__ __launch_bounds__(256) void prep_w3(
    const float* __restrict__ W1, const float* __restrict__ W2, const float* __restrict__ W3,
    unsigned short* __restrict__ Wf1, unsigned short* __restrict__ Wf2, unsigned short* __restrict__ Wf3)
{
    const float* W; unsigned short* Wf; int K, M;
    if (blockIdx.x == 0)      { W = W1; Wf = Wf1; K = 128; M = 64; }
    else if (blockIdx.x == 1) { W = W2; Wf = Wf2; K = 64;  M = 64; }
    else                      { W = W3; Wf = Wf3; K = 64;  M = 40; }
    const int NT = (M + 15) >> 4, NTC = NT << 4, KS = K >> 5;
    for (int i = threadIdx.x; i < K * NTC; i += 256) {
        int k = i / NTC, nn = i - k * NTC;
        unsigned short hv = 0;
        if (nn < M) hv = f32_to_f16u(W[(size_t)k * M + nn]);
        int s = k >> 5, q = (k >> 3) & 3, j = k & 7;
        int u = nn >> 4, lane = (q << 4) | (nn & 15);
        Wf[((u * KS + s) << 9) + (lane << 3) + j] = hv;
    }
}

// ==================== MFMA GEMM, B held in registers ====================
// H[v][m] = f16( dinv[v] * sum_k X[v][k] * W[k][m] ), H row stride 64, pad cols zeroed.

template<int KK, int NT, bool INF32>
__global__ __launch_bounds__(256) void gemm_t(
    const void* __restrict__ Xin, const unsigned short* __restrict__ Wf,
    const float* __restrict__ dinv, unsigned short* __restrict__ H, int n)
{
    constexpr int KS = KK >> 5;
    __shared__ __align__(16) unsigned short ldsA[4 * KS * 512];
    const int tid = threadIdx.x;
    const int n0  = blockIdx.x * 64;

    // B fragments: loop-invariant, straight from global (L2-hot, 16 B/lane)
    half8 bf[NT * KS];
    {
        const int lane = tid & 63;
        #pragma unroll
        for (int u = 0; u < NT; ++u)
            #pragma unroll
            for (int s = 0; s < KS; ++s)
                bf[u * KS + s] = *(const half8*)&Wf[((u * KS + s) << 9) + (lane << 3)];
    }

    // ---- stage X/A tile (64 rows x KK) as A-fragments ----
    {
        const int rl = tid >> 3;
        const int kl = tid & 7;
        #pragma unroll
        for (int rb = 0; rb < 64; rb += 32) {
            int r = rl + rb;
            int node = n0 + r;
            int t = r >> 4, m = r & 15;
            #pragma unroll
            for (int kq8 = 0; kq8 < (KK >> 2); kq8 += 8) {
                int k0 = (kl + kq8) << 2;
                unsigned short h[4] = {0, 0, 0, 0};
                if (node < n) {
                    if (INF32) {
                        const float* xp = (const float*)Xin + (size_t)node * KK + k0;
                        float4v v = *(const float4v*)xp;
                        #pragma unroll
                        for (int i = 0; i < 4; ++i) h[i] = f32_to_f16u(v[i]);
                    } else {
                        const unsigned int* ap =
                            (const unsigned int*)Xin + (((size_t)node * KK + k0) >> 1);
                        uint2 v = *(const uint2*)ap;
                        h[0] = (unsigned short)(v.x & 0xffff);
                        h[1] = (unsigned short)(v.x >> 16);
                        h[2] = (unsigned short)(v.y & 0xffff);
                        h[3] = (unsigned short)(v.y >> 16);
                    }
                }
                int s = k0 >> 5, q = (k0 >> 3) & 3, j0 = k0 & 7;
                int lane = (q << 4) | m;
                unsigned short* p = &ldsA[((t * KS + s) << 9) + (lane << 3) + j0];
                unsigned int lo = (unsigned int)h[0] | ((unsigned int)h[1] << 16);
                unsigned int hi = (unsigned int)h[2] | ((unsigned int)h[3] << 16);
                *(uint2*)p = make_uint2(lo, hi);
            }
        }
    }

    __syncthreads();

    const int wv   = tid >> 6;
    const int lane = tid & 63;
    float4v acc[NT];
    #pragma unroll
    for (int u = 0; u < NT; ++u) acc[u] = (float4v){0.f, 0.f, 0.f, 0.f};

    #pragma unroll
    for (int s = 0; s < KS; ++s) {
        half8 a = *(const half8*)&ldsA[((wv * KS + s) << 9) + (lane << 3)];
        #pragma unroll
        for (int u = 0; u < NT; ++u)
            acc[u] = __builtin_amdgcn_mfma_f32_16x16x32_f16(a, bf[u * KS + s], acc[u], 0, 0, 0);
    }

    // ---- epilogue: scale by dinv, f16 store, stride 64 (pad zeros) ----
    const int mcol = lane & 15;
    const int quad = lane >> 4;
    #pragma unroll
    for (int reg = 0; reg < 4; ++reg) {
        int node = n0 + (wv << 4) + (quad << 2) + reg;
        if (node >= n) continue;
        float dv = dinv[node];
        #pragma unroll
        for (int u = 0; u < 4; ++u) {
            int col = (u << 4) + mcol;
            float val = (u < NT) ? acc[u < NT ? u : 0][reg] * dv : 0.0f;
            H[(size_t)node * 64 + col] = f32_to_f16u(val);
        }
    }
}

// ==================== persistent gather: 2 nodes/wave, fdot2 accumulate ====================
// A[v] = relu?( b + dinv[v]*(H[v] + sum H[s]) ); SOFTMAX variant fuses
// relu + log_softmax and writes f32 output (MOUT cols).

template<int MOUT, bool RELU_OUT, bool SOFTMAX>
__global__ __launch_bounds__(256) void gather_t(
    const int* __restrict__ rp, const int* __restrict__ es,
    const unsigned short* __restrict__ H, const float* __restrict__ dinv,
    const float* __restrict__ bias, void* __restrict__ Aout, int n)
{
    const int lane = threadIdx.x & 63;
    const int half = lane >> 5;
    const int slot = (lane >> 3) & 3;
    const int c8   = lane & 7;
    const uint4* H4 = (const uint4*)H;
    const half2v mlo = {(_Float16)1.0f, (_Float16)0.0f};
    const half2v mhi = {(_Float16)0.0f, (_Float16)1.0f};

    float bi[8];
    #pragma unroll
    for (int i = 0; i < 8; ++i) {
        int col = (c8 << 3) + i;
        bi[i] = (col < MOUT) ? bias[col] : 0.0f;
    }

    const int TW2 = (int)(gridDim.x << 3);   // 4 waves/block * 2 nodes
    for (int nb = (((int)blockIdx.x << 2) + (threadIdx.x >> 6)) << 1; nb < n; nb += TW2) {
        const int node = nb + half;           // n even -> always < n
        float a[8] = {0.f, 0.f, 0.f, 0.f, 0.f, 0.f, 0.f, 0.f};

        const int e0 = rp[node], e1 = rp[node + 1];

        if (slot == 0) {                      // self loop
            uint4 u = H4[(size_t)node * 8 + c8];
            a[0] = fdot2u(u.x, mlo, a[0]); a[1] = fdot2u(u.x, mhi, a[1]);
            a[2] = fdot2u(u.y, mlo, a[2]); a[3] = fdot2u(u.y, mhi, a[3]);
            a[4] = fdot2u(u.z, mlo, a[4]); a[5] = fdot2u(u.z, mhi, a[5]);
            a[6] = fdot2u(u.w, mlo, a[6]); a[7] = fdot2u(u.w, mhi, a[7]);
        }

        for (int base = e0; base < e1; base += 4) {
            int idx = base + slot;
            if (idx < e1) {
                int s = es[idx];
                uint4 u = H4[(size_t)s * 8 + c8];
                a[0] = fdot2u(u.x, mlo, a[0]); a[1] = fdot2u(u.x, mhi, a[1]);
                a[2] = fdot2u(u.y, mlo, a[2]); a[3] = fdot2u(u.y, mhi, a[3]);
                a[4] = fdot2u(u.z, mlo, a[4]); a[5] = fdot2u(u.z, mhi, a[5]);
                a[6] = fdot2u(u.w, mlo, a[6]); a[7] = fdot2u(u.w, mhi, a[7]);
            }
        }

        #pragma unroll
        for (int i = 0; i < 8; ++i) {        // reduce across 4 slots (stay in half)
            a[i] += __shfl_xor(a[i], 8, 64);
            a[i] += __shfl_xor(a[i], 16, 64);
        }

        const float dv = dinv[node];

        if (!SOFTMAX) {
            if (slot == 0) {
                unsigned short o[8];
                #pragma unroll
                for (int i = 0; i < 8; ++i) {
                    float v = a[i] * dv + bi[i];
                    if (RELU_OUT) v = fmaxf(v, 0.0f);
                    o[i] = f32_to_f16u(v);
                }
                uint4 w;
                w.x = (unsigned int)o[0] | ((unsigned int)o[1] << 16);
                w.y = (unsigned int)o[2] | ((unsigned int)o[3] << 16);
                w.z = (unsigned int)o[4] | ((unsigned int)o[5] << 16);
                w.w = (unsigned int)o[6] | ((unsigned int)o[7] << 16);
                ((uint4*)Aout)[(size_t)node * 8 + c8] = w;
            }
        } else {
            float z[8]; float m = -INFINITY;
            #pragma unroll
            for (int i = 0; i < 8; ++i) {
                int col = (c8 << 3) + i;
                z[i] = (col < MOUT) ? fmaxf(a[i] * dv + bi[i], 0.0f) : -INFINITY;
                m = fmaxf(m, z[i]);
            }
            m = fmaxf(m, __shfl_xor(m, 1, 64));
            m = fmaxf(m, __shfl_xor(m, 2, 64));
            m = fmaxf(m, __shfl_xor(m, 4, 64));
            float s = 0.0f;
            #pragma unroll
            for (int i = 0; i < 8; ++i) s += expf(z[i] - m);   // -inf -> 0
            s += __shfl_xor(s, 1, 64);
            s += __shfl_xor(s, 2, 64);
            s += __shfl_xor(s, 4, 64);
            float ls = logf(s) + m;
            if (slot == 0 && c8 < (MOUT + 7) / 8) {
                float* op = (float*)Aout + (size_t)node * MOUT + (c8 << 3);
                float4v o0 = {z[0] - ls, z[1] - ls, z[2] - ls, z[3] - ls};
                float4v o1 = {z[4] - ls, z[5] - ls, z[6] - ls, z[7] - ls};
                *(float4v*)op = o0;
                *(float4v*)(op + 4) = o1;
            }
        }
    }
}

// ==================== launch ====================

extern "C" void kernel_launch(void* const* d_in, const int* in_sizes, int n_in,
                              void* d_out, int out_size, void* d_ws, size_t ws_size,
                              hipStream_t stream)
{
    const float* x  = (const float*)d_in[0];
    const int*   ei = (const int*)  d_in[1];
    const float* W1 = (const float*)d_in[2];
    const float* b1 = (const float*)d_in[3];
    const float* W2 = (const float*)d_in[4];
    const float* b2 = (const float*)d_in[5];
    const float* W3 = (const float*)d_in[6];
    const float* b3 = (const float*)d_in[7];

    const int F_IN = 128;
    const int n = in_sizes[0] / F_IN;      // 100000
    const int E = in_sizes[1] / 2;         // 1600000
    const int* src = ei;
    const int* dst = ei + E;
    float* out = (float*)d_out;

    const int NB = (n + 255) >> 8;         // buckets of 256 nodes (<=512)

    // ---- workspace layout ----
    auto align = [](size_t v) { return (v + 255) & ~(size_t)255; };
    char* w = (char*)d_ws;
    size_t off = 0;
    float*          dinv = (float*)(w + off);          off = align(off + (size_t)n * 4);
    unsigned short* H    = (unsigned short*)(w + off); off = align(off + (size_t)n * 64 * 2);
    unsigned short* A    = (unsigned short*)(w + off); off = align(off + (size_t)n * 64 * 2);
    int*            rp   = (int*)(w + off);            off = align(off + (size_t)(n + 1) * 4);
    int*            es   = (int*)(w + off);            off = align(off + (size_t)E * 4);
    unsigned int*   bint = (unsigned int*)(w + off);   off = align(off + (size_t)E * 4);
    int*            bcnt = (int*)(w + off);            off = align(off + (size_t)512 * 4);
    int*            boff = (int*)(w + off);            off = align(off + (size_t)513 * 4);
    int*            bcur = (int*)(w + off);            off = align(off + (size_t)512 * 4);
    unsigned short* Wf1  = (unsigned short*)(w + off); off = align(off + (size_t)8192 * 2);
    unsigned short* Wf2  = (unsigned short*)(w + off); off = align(off + (size_t)4096 * 2);
    unsigned short* Wf3  = (unsigned short*)(w + off); off = align(off + (size_t)3072 * 2);

    const int BLK = 256;
    auto cdiv = [](int a, int b) { return (a + b - 1) / b; };
    const int EB = cdiv(E, 2048);

    // ---- CSR build + weight preformat ----
    prep_w3    <<<3, BLK, 0, stream>>>(W1, W2, W3, Wf1, Wf2, Wf3);
    zero_int   <<<cdiv(NB, BLK), BLK, 0, stream>>>(bcnt, NB);
    hist_bucket<<<EB, BLK, 0, stream>>>(dst, bcnt, E, NB);
    scan_nb    <<<1, 512, 0, stream>>>(bcnt, boff, bcur, rp, NB, n, E);
    bin_edges  <<<EB, BLK, 0, stream>>>(src, dst, bcur, bint, E, NB);
    build_csr  <<<NB, BLK, 0, stream>>>(bint, boff, rp, dinv, es, n);

    const int GB = cdiv(n, 64);
    const int GG = 2048;   // persistent gather grid

    // ---- layer 1 ----
    gemm_t<128, 4, true> <<<GB, BLK, 0, stream>>>(x, Wf1, dinv, H, n);
    gather_t<64, true, false><<<GG, BLK, 0, stream>>>(rp, es, H, dinv, b1, A, n);

    // ---- layer 2 ----
    gemm_t<64, 4, false> <<<GB, BLK, 0, stream>>>(A, Wf2, dinv, H, n);
    gather_t<64, true, false><<<GG, BLK, 0, stream>>>(rp, es, H, dinv, b2, A, n);

    // ---- layer 3 + fused relu/log_softmax -> f32 out ----
    gemm_t<64, 3, false> <<<GB, BLK, 0, stream>>>(A, Wf3, dinv, H, n);
    gather_t<40, false, true><<<GG, BLK, 0, stream>>>(rp, es, H, dinv, b3, out, n);
}

// Round 6
// 293.338 us; speedup vs baseline: 4.6969x; 1.1331x over previous
//
#include <hip/hip_runtime.h>
#include <math.h>

typedef _Float16 half2v  __attribute__((ext_vector_type(2)));
typedef _Float16 half8   __attribute__((ext_vector_type(8)));
typedef float    float4v __attribute__((ext_vector_type(4)));

static __device__ __forceinline__ unsigned short f32_to_f16u(float f) {
    _Float16 h = (_Float16)f;
    return __builtin_bit_cast(unsigned short, h);
}

// ==================== bucketed CSR build ====================

__global__ void zero_int(int* __restrict__ p, int n) {
    int i = blockIdx.x * blockDim.x + threadIdx.x;
    if (i < n) p[i] = 0;
}

// Pass A: per-block LDS histogram of dst>>8 (4096 edges/block)
__global__ __launch_bounds__(256) void hist_bucket(
    const int* __restrict__ dst, int* __restrict__ bcnt, int E, int NB)
{
    __shared__ int h[512];
    const int tid = threadIdx.x;
    h[tid] = 0; h[tid + 256] = 0;
    __syncthreads();
    const int base = blockIdx.x * 4096 + tid;
    #pragma unroll
    for (int k = 0; k < 16; ++k) {
        int i = base + k * 256;
        if (i < E) atomicAdd(&h[dst[i] >> 8], 1);
    }
    __syncthreads();
    for (int j = tid; j < NB; j += 256)
        if (h[j]) atomicAdd(&bcnt[j], h[j]);
}

__global__ __launch_bounds__(512) void scan_nb(
    const int* __restrict__ bcnt, int* __restrict__ boff, int* __restrict__ bcur,
    int* __restrict__ rp, int NB, int n, int E)
{
    __shared__ int s[512];
    const int tid = threadIdx.x;
    int v = (tid < NB) ? bcnt[tid] : 0;
    s[tid] = v;
    __syncthreads();
    for (int off = 1; off < 512; off <<= 1) {
        int x = (tid >= off) ? s[tid - off] : 0;
        __syncthreads();
        s[tid] += x;
        __syncthreads();
    }
    int excl = s[tid] - v;
    if (tid < NB) { boff[tid] = excl; bcur[tid] = excl; }
    if (tid == NB - 1) boff[NB] = excl + v;
    if (tid == 0) rp[n] = E;
}

// Pass B: scatter packed (src<<8 | dst&255) into bucket regions (4096 edges/block)
__global__ __launch_bounds__(256) void bin_edges(
    const int* __restrict__ src, const int* __restrict__ dst,
    int* __restrict__ bcur, unsigned int* __restrict__ bint, int E, int NB)
{
    __shared__ int h[512];
    __shared__ int rbase[512];
    const int tid = threadIdx.x;
    h[tid] = 0; h[tid + 256] = 0;
    __syncthreads();
    const int eb = blockIdx.x * 4096 + tid;
    int d[16], sr[16];
    #pragma unroll
    for (int k = 0; k < 16; ++k) {
        int i = eb + k * 256;
        if (i < E) {
            d[k] = dst[i]; sr[k] = src[i];
            atomicAdd(&h[d[k] >> 8], 1);
        } else d[k] = -1;
    }
    __syncthreads();
    for (int j = tid; j < NB; j += 256) {
        int c = h[j];
        rbase[j] = c ? atomicAdd(&bcur[j], c) : 0;
        h[j] = 0;
    }
    __syncthreads();
    #pragma unroll
    for (int k = 0; k < 16; ++k) {
        if (d[k] >= 0) {
            int bkt = d[k] >> 8;
            int pos = rbase[bkt] + atomicAdd(&h[bkt], 1);
            bint[pos] = ((unsigned int)sr[k] << 8) | (unsigned int)(d[k] & 255);
        }
    }
}

// Pass C: one block per bucket -> rp, dinv, es
__global__ __launch_bounds__(256) void build_csr(
    const unsigned int* __restrict__ bint, const int* __restrict__ boff,
    int* __restrict__ rp, float* __restrict__ dinv, int* __restrict__ es, int n)
{
    __shared__ int cnt[256];
    __shared__ int sc[256];
    __shared__ int cur[256];
    const int b = blockIdx.x, tid = threadIdx.x;
    const int e0 = boff[b], e1 = boff[b + 1];

    cnt[tid] = 0;
    __syncthreads();
    for (int i = e0 + tid; i < e1; i += 256)
        atomicAdd(&cnt[bint[i] & 255], 1);
    __syncthreads();

    int v = cnt[tid];
    sc[tid] = v;
    __syncthreads();
    for (int off = 1; off < 256; off <<= 1) {
        int x = (tid >= off) ? sc[tid - off] : 0;
        __syncthreads();
        sc[tid] += x;
        __syncthreads();
    }
    int excl = sc[tid] - v;
    int node = (b << 8) + tid;
    if (node < n) {
        rp[node]   = e0 + excl;
        dinv[node] = rsqrtf((float)(v + 1));
    }
    cur[tid] = e0 + excl;
    __syncthreads();

    for (int i = e0 + tid; i < e1; i += 256) {
        unsigned int p = bint[i];
        int pos = atomicAdd(&cur[p & 255], 1);
        es[pos] = (int)(p >> 8);
    }
}

// ==================== W -> B-fragment preformat ====================

__global__ __launch_bounds__(256) void prep_w3(
    const float* __restrict__ W1, const float* __restrict__ W2, const float* __restrict__ W3,
    unsigned short* __restrict__ Wf1, unsigned short* __restrict__ Wf2, unsigned short* __restrict__ Wf3)
{
    const float* W; unsigned short* Wf; int K, M;
    if (blockIdx.x == 0)      { W = W1; Wf = Wf1; K = 128; M = 64; }
    else if (blockIdx.x == 1) { W = W2; Wf = Wf2; K = 64;  M = 64; }
    else                      { W = W3; Wf = Wf3; K = 64;  M = 40; }
    const int NT = (M + 15) >> 4, NTC = NT << 4, KS = K >> 5;
    for (int i = threadIdx.x; i < K * NTC; i += 256) {
        int k = i / NTC, nn = i - k * NTC;
        unsigned short hv = 0;
        if (nn < M) hv = f32_to_f16u(W[(size_t)k * M + nn]);
        int s = k >> 5, q = (k >> 3) & 3, j = k & 7;
        int u = nn >> 4, lane = (q << 4) | (nn & 15);
        Wf[((u * KS + s) << 9) + (lane << 3) + j] = hv;
    }
}

// ==================== MFMA GEMM, B in registers ====================
// H[v][col] = f16( dinv[v] * sum_k X[v][k]*W[k][col] ), row stride STRIDE f16.

template<int KK, int NT, int STRIDE, int MOUT, bool INF32>
__global__ __launch_bounds__(256) void gemm_t(
    const void* __restrict__ Xin, const unsigned short* __restrict__ Wf,
    const float* __restrict__ dinv, unsigned short* __restrict__ H, int n)
{
    constexpr int KS = KK >> 5;
    __shared__ __align__(16) unsigned short ldsA[4 * KS * 512];
    const int tid = threadIdx.x;
    const int n0  = blockIdx.x * 64;

    half8 bf[NT * KS];
    {
        const int lane = tid & 63;
        #pragma unroll
        for (int u = 0; u < NT; ++u)
            #pragma unroll
            for (int s = 0; s < KS; ++s)
                bf[u * KS + s] = *(const half8*)&Wf[((u * KS + s) << 9) + (lane << 3)];
    }

    {
        const int rl = tid >> 3;
        const int kl = tid & 7;
        #pragma unroll
        for (int rb = 0; rb < 64; rb += 32) {
            int r = rl + rb;
            int node = n0 + r;
            int t = r >> 4, m = r & 15;
            #pragma unroll
            for (int kq8 = 0; kq8 < (KK >> 2); kq8 += 8) {
                int k0 = (kl + kq8) << 2;
                unsigned short h[4] = {0, 0, 0, 0};
                if (node < n) {
                    if (INF32) {
                        const float* xp = (const float*)Xin + (size_t)node * KK + k0;
                        float4v v = *(const float4v*)xp;
                        #pragma unroll
                        for (int i = 0; i < 4; ++i) h[i] = f32_to_f16u(v[i]);
                    } else {
                        const unsigned int* ap =
                            (const unsigned int*)Xin + (((size_t)node * KK + k0) >> 1);
                        uint2 v = *(const uint2*)ap;
                        h[0] = (unsigned short)(v.x & 0xffff);
                        h[1] = (unsigned short)(v.x >> 16);
                        h[2] = (unsigned short)(v.y & 0xffff);
                        h[3] = (unsigned short)(v.y >> 16);
                    }
                }
                int s = k0 >> 5, q = (k0 >> 3) & 3, j0 = k0 & 7;
                int lane = (q << 4) | m;
                unsigned short* p = &ldsA[((t * KS + s) << 9) + (lane << 3) + j0];
                unsigned int lo = (unsigned int)h[0] | ((unsigned int)h[1] << 16);
                unsigned int hi = (unsigned int)h[2] | ((unsigned int)h[3] << 16);
                *(uint2*)p = make_uint2(lo, hi);
            }
        }
    }

    __syncthreads();

    const int wv   = tid >> 6;
    const int lane = tid & 63;
    float4v acc[NT];
    #pragma unroll
    for (int u = 0; u < NT; ++u) acc[u] = (float4v){0.f, 0.f, 0.f, 0.f};

    #pragma unroll
    for (int s = 0; s < KS; ++s) {
        half8 a = *(const half8*)&ldsA[((wv * KS + s) << 9) + (lane << 3)];
        #pragma unroll
        for (int u = 0; u < NT; ++u)
            acc[u] = __builtin_amdgcn_mfma_f32_16x16x32_f16(a, bf[u * KS + s], acc[u], 0, 0, 0);
    }

    const int mcol = lane & 15;
    const int quad = lane >> 4;
    #pragma unroll
    for (int reg = 0; reg < 4; ++reg) {
        int node = n0 + (wv << 4) + (quad << 2) + reg;
        if (node >= n) continue;
        float dv = dinv[node];
        #pragma unroll
        for (int u = 0; u < NT; ++u) {
            int col = (u << 4) + mcol;
            if (col < MOUT)
                H[(size_t)node * STRIDE + col] = f32_to_f16u(acc[u][reg] * dv);
        }
    }
}

// ==================== persistent gather v3 ====================
// 2 nodes/wave (halves), 4 slots x 8 chunk-lanes per node.
// Edge indices preloaded 32 at a time per half; pk_f16 accumulation.
// ROWU4 = uint4 chunks per H row (8 for stride-64, 5 for stride-40).

template<int MOUT, int ROWU4, bool RELU_OUT, bool SOFTMAX>
__global__ __launch_bounds__(256) void gather_t(
    const int* __restrict__ rp, const int* __restrict__ es,
    const unsigned short* __restrict__ H, const float* __restrict__ dinv,
    const float* __restrict__ bias, void* __restrict__ Aout, int n)
{
    const int lane   = threadIdx.x & 63;
    const int half   = lane >> 5;
    const int lane32 = lane & 31;
    const int slot   = (lane >> 3) & 3;
    const int c8     = lane & 7;
    const bool act   = c8 < ROWU4;
    const uint4* H4  = (const uint4*)H;

    float bi[8];
    #pragma unroll
    for (int i = 0; i < 8; ++i) {
        int col = (c8 << 3) + i;
        bi[i] = (col < MOUT) ? bias[col] : 0.0f;
    }

    const half8 hz = {(_Float16)0, (_Float16)0, (_Float16)0, (_Float16)0,
                      (_Float16)0, (_Float16)0, (_Float16)0, (_Float16)0};

    const int TW2 = (int)(gridDim.x << 3);
    for (int nb = (((int)blockIdx.x << 2) + ((int)threadIdx.x >> 6)) << 1; nb < n; nb += TW2) {
        const int node = nb + half;
        const int e0 = rp[node], e1 = rp[node + 1];
        const float dv = dinv[node];

        half8 hacc = hz;
        if (slot == 0 && act)
            hacc = __builtin_bit_cast(half8, H4[(size_t)node * ROWU4 + c8]);

        for (int cb = e0; cb < e1; cb += 32) {
            const int rem = e1 - cb;
            int eidx = cb + lane32; if (eidx > e1 - 1) eidx = e1 - 1;
            const int ei = es[eidx];
            #pragma unroll
            for (int j = 0; j < 8; ++j) {
                const int idx = (j << 2) + slot;
                const int s = __shfl(ei, (half << 5) + idx, 64);
                if (idx < rem && act) {
                    uint4 u = H4[(size_t)s * ROWU4 + c8];
                    hacc = hacc + __builtin_bit_cast(half8, u);
                }
            }
        }

        // reduce across 4 slots (xor 8, 16)
        #pragma unroll
        for (int step = 8; step <= 16; step <<= 1) {
            uint4 u = __builtin_bit_cast(uint4, hacc);
            uint4 o;
            o.x = __shfl_xor(u.x, step, 64);
            o.y = __shfl_xor(u.y, step, 64);
            o.z = __shfl_xor(u.z, step, 64);
            o.w = __shfl_xor(u.w, step, 64);
            hacc = hacc + __builtin_bit_cast(half8, o);
        }

        if (!SOFTMAX) {
            if (slot == 0) {
                unsigned short o[8];
                #pragma unroll
                for (int i = 0; i < 8; ++i) {
                    float v = (float)hacc[i] * dv + bi[i];
                    if (RELU_OUT) v = fmaxf(v, 0.0f);
                    o[i] = f32_to_f16u(v);
                }
                uint4 w;
                w.x = (unsigned int)o[0] | ((unsigned int)o[1] << 16);
                w.y = (unsigned int)o[2] | ((unsigned int)o[3] << 16);
                w.z = (unsigned int)o[4] | ((unsigned int)o[5] << 16);
                w.w = (unsigned int)o[6] | ((unsigned int)o[7] << 16);
                ((uint4*)Aout)[(size_t)node * 8 + c8] = w;
            }
        } else {
            float z[8]; float m = -INFINITY;
            #pragma unroll
            for (int i = 0; i < 8; ++i) {
                int col = (c8 << 3) + i;
                z[i] = (col < MOUT && act) ? fmaxf((float)hacc[i] * dv + bi[i], 0.0f)
                                           : -INFINITY;
                m = fmaxf(m, z[i]);
            }
            m = fmaxf(m, __shfl_xor(m, 1, 64));
            m = fmaxf(m, __shfl_xor(m, 2, 64));
            m = fmaxf(m, __shfl_xor(m, 4, 64));
            float s = 0.0f;
            #pragma unroll
            for (int i = 0; i < 8; ++i) s += expf(z[i] - m);
            s += __shfl_xor(s, 1, 64);
            s += __shfl_xor(s, 2, 64);
            s += __shfl_xor(s, 4, 64);
            float ls = logf(s) + m;
            if (slot == 0 && c8 < (MOUT + 7) / 8) {
                float* op = (float*)Aout + (size_t)node * MOUT + (c8 << 3);
                float4v o0 = {z[0] - ls, z[1] - ls, z[2] - ls, z[3] - ls};
                float4v o1 = {z[4] - ls, z[5] - ls, z[6] - ls, z[7] - ls};
                *(float4v*)op = o0;
                *(float4v*)(op + 4) = o1;
            }
        }
    }
}

// ==================== launch ====================

extern "C" void kernel_launch(void* const* d_in, const int* in_sizes, int n_in,
                              void* d_out, int out_size, void* d_ws, size_t ws_size,
                              hipStream_t stream)
{
    const float* x  = (const float*)d_in[0];
    const int*   ei = (const int*)  d_in[1];
    const float* W1 = (const float*)d_in[2];
    const float* b1 = (const float*)d_in[3];
    const float* W2 = (const float*)d_in[4];
    const float* b2 = (const float*)d_in[5];
    const float* W3 = (const float*)d_in[6];
    const float* b3 = (const float*)d_in[7];

    const int F_IN = 128;
    const int n = in_sizes[0] / F_IN;      // 100000
    const int E = in_sizes[1] / 2;         // 1600000
    const int* src = ei;
    const int* dst = ei + E;
    float* out = (float*)d_out;

    const int NB = (n + 255) >> 8;

    auto align = [](size_t v) { return (v + 255) & ~(size_t)255; };
    char* w = (char*)d_ws;
    size_t off = 0;
    float*          dinv = (float*)(w + off);          off = align(off + (size_t)n * 4);
    unsigned short* H    = (unsigned short*)(w + off); off = align(off + (size_t)n * 64 * 2);
    unsigned short* A    = (unsigned short*)(w + off); off = align(off + (size_t)n * 64 * 2);
    int*            rp   = (int*)(w + off);            off = align(off + (size_t)(n + 1) * 4);
    int*            es   = (int*)(w + off);            off = align(off + (size_t)E * 4);
    unsigned int*   bint = (unsigned int*)(w + off);   off = align(off + (size_t)E * 4);
    int*            bcnt = (int*)(w + off);            off = align(off + (size_t)512 * 4);
    int*            boff = (int*)(w + off);            off = align(off + (size_t)513 * 4);
    int*            bcur = (int*)(w + off);            off = align(off + (size_t)512 * 4);
    unsigned short* Wf1  = (unsigned short*)(w + off); off = align(off + (size_t)8192 * 2);
    unsigned short* Wf2  = (unsigned short*)(w + off); off = align(off + (size_t)4096 * 2);
    unsigned short* Wf3  = (unsigned short*)(w + off); off = align(off + (size_t)3072 * 2);

    const int BLK = 256;
    auto cdiv = [](int a, int b) { return (a + b - 1) / b; };
    const int EB = cdiv(E, 4096);

    prep_w3    <<<3, BLK, 0, stream>>>(W1, W2, W3, Wf1, Wf2, Wf3);
    zero_int   <<<cdiv(NB, BLK), BLK, 0, stream>>>(bcnt, NB);
    hist_bucket<<<EB, BLK, 0, stream>>>(dst, bcnt, E, NB);
    scan_nb    <<<1, 512, 0, stream>>>(bcnt, boff, bcur, rp, NB, n, E);
    bin_edges  <<<EB, BLK, 0, stream>>>(src, dst, bcur, bint, E, NB);
    build_csr  <<<NB, BLK, 0, stream>>>(bint, boff, rp, dinv, es, n);

    const int GB = cdiv(n, 64);
    const int GG = 2048;

    // ---- layer 1 ----
    gemm_t<128, 4, 64, 64, true> <<<GB, BLK, 0, stream>>>(x, Wf1, dinv, H, n);
    gather_t<64, 8, true, false><<<GG, BLK, 0, stream>>>(rp, es, H, dinv, b1, A, n);

    // ---- layer 2 ----
    gemm_t<64, 4, 64, 64, false> <<<GB, BLK, 0, stream>>>(A, Wf2, dinv, H, n);
    gather_t<64, 8, true, false><<<GG, BLK, 0, stream>>>(rp, es, H, dinv, b2, A, n);

    // ---- layer 3 (H packed at stride 40) + fused relu/log_softmax ----
    gemm_t<64, 3, 40, 40, false> <<<GB, BLK, 0, stream>>>(A, Wf3, dinv, H, n);
    gather_t<40, 5, false, true><<<GG, BLK, 0, stream>>>(rp, es, H, dinv, b3, out, n);
}